// Round 6
// baseline (653.045 us; speedup 1.0000x reference)
//
#include <hip/hip_runtime.h>
#include <stdint.h>

#define M_DIM 4096
#define K_DIM 4096
#define N_DIM 11008
#define KP    512              // 16B slots (8 fp16) per K row
#define NT    128              // K tiles of 32
#define BM    256
#define BN    128

#define QP_BYTES   (11008u * 512u * 4u)
#define XW_OFFSET  25165824u
#define XW_BYTES   (4096u * 4096u * 2u)
#define WS_NEEDED  (XW_OFFSET + XW_BYTES)

typedef __attribute__((ext_vector_type(8))) _Float16 f16x8;
typedef __attribute__((ext_vector_type(2))) _Float16 f16x2;
typedef __attribute__((ext_vector_type(4))) float    f32x4;

// ---------- pre-pass 1: qweight int32 [N][K] -> nibble-interleaved u32 [N][K/8] ----------
// [3:0]=e0 [7:4]=e2 [11:8]=e4 [15:12]=e6 [19:16]=e1 [23:20]=e3 [27:24]=e5 [31:28]=e7
__global__ void pack_qw(const int* __restrict__ qw, unsigned int* __restrict__ qp) {
    int stride = gridDim.x * blockDim.x;
    for (int i = blockIdx.x * blockDim.x + threadIdx.x; i < N_DIM * KP; i += stride) {
        const int* src = qw + (size_t)i * 8;
        int4 a = *(const int4*)src;
        int4 b = *(const int4*)(src + 4);
        unsigned int w = (unsigned)a.x | ((unsigned)a.z << 4) | ((unsigned)b.x << 8) | ((unsigned)b.z << 12)
                       | ((unsigned)a.y << 16) | ((unsigned)a.w << 20) | ((unsigned)b.y << 24) | ((unsigned)b.w << 28);
        qp[i] = w;
    }
}

// ---------- pre-pass 2: x fp32 -> fp16 slots (plain layout, no swizzle) ----------
__global__ void cvt_x(const float* __restrict__ x, uint4* __restrict__ xw) {
    int stride = gridDim.x * blockDim.x;
    for (int i = blockIdx.x * blockDim.x + threadIdx.x; i < M_DIM * KP; i += stride) {
        const float* src = x + (size_t)i * 8;
        float4 f0 = *(const float4*)src;
        float4 f1 = *(const float4*)(src + 4);
        union { _Float16 h[8]; uint4 v; } pk;
        pk.h[0]=(_Float16)f0.x; pk.h[1]=(_Float16)f0.y;
        pk.h[2]=(_Float16)f0.z; pk.h[3]=(_Float16)f0.w;
        pk.h[4]=(_Float16)f1.x; pk.h[5]=(_Float16)f1.y;
        pk.h[6]=(_Float16)f1.z; pk.h[7]=(_Float16)f1.w;
        xw[i] = pk.v;
    }
}

// ---------- dequant 8 nibbles -> 4 fp16x2 ----------
__device__ __forceinline__ uint4 dq8(unsigned int w, f16x2 s2, f16x2 z2) {
    const f16x2 k1024 = {(_Float16)1024.0f, (_Float16)1024.0f};
    union { f16x2 h; unsigned int u; } p0, p1, p2, p3;
    p0.u = 0x64006400u | (w & 0x000F000Fu);
    p1.u = 0x64006400u | ((w >> 4)  & 0x000F000Fu);
    p2.u = 0x64006400u | ((w >> 8)  & 0x000F000Fu);
    p3.u = 0x64006400u | ((w >> 12) & 0x000F000Fu);
    union { f16x2 h2[4]; uint4 v; } r;
    r.h2[0] = (p0.h - k1024) * s2 + z2;
    r.h2[1] = (p1.h - k1024) * s2 + z2;
    r.h2[2] = (p2.h - k1024) * s2 + z2;
    r.h2[3] = (p3.h - k1024) * s2 + z2;
    return r.v;
}

#define MFMA16(d, va, vb) d = __builtin_amdgcn_mfma_f32_16x16x32_f16(va, vb, d, 0, 0, 0)

// ---------- main GEMM: 256x128 tile, BK=32, 2-phase dbuf, counted vmcnt ----------
__global__ __launch_bounds__(256, 2) void wq_gemm_p2(
    const uint4*  __restrict__ xw,     // fp16 [M][512] slots
    const uint2*  __restrict__ qp2,    // packed u32 [N][512] viewed as uint2 [N][256]
    const float*  __restrict__ scales, // fp32 [32][N]
    const float*  __restrict__ zeros,  // fp32 [32][N]
    const float*  __restrict__ bias,   // fp32 [N]
    float*        __restrict__ out)    // fp32 [M][N]
{
    // [buf][k-slot][row], +1 uint4 pad per slot row-array -> conflict-free b128 reads
    __shared__ __align__(16) uint4 Asl[2][4][257];   // 32.9 KB
    __shared__ __align__(16) uint4 Bsl[2][4][129];   // 16.5 KB

    const int tid  = threadIdx.x;
    const int lane = tid & 63;
    const int wid  = tid >> 6;
    const int wm   = wid >> 1;          // 0..1
    const int wn   = wid & 1;           // 0..1
    const int l15  = lane & 15;
    const int l4   = lane >> 4;         // k-slot 0..3

    // XCD-aware bijective swizzle: 1376 = 8 * 172
    int id  = blockIdx.x;
    int swz = (id & 7) * 172 + (id >> 3);
    const int m0 = (swz & 15) * BM;     // 16 m-blocks
    const int n0 = (swz >> 4) * BN;     // 86 n-blocks

    const int brow  = tid >> 1;         // 0..127
    const int bhalf = tid & 1;

    f32x4 acc[8][4] = {};

    auto stageA = [&](int tc, int buf) {
        #pragma unroll
        for (int i = 0; i < 4; ++i) {
            int unit = wid * 4 + i;     // 0..15
            int slot = unit & 3;
            int rh   = unit >> 2;       // 0..3 (64-row half)
            const uint4* src = xw + (size_t)(m0 + rh * 64 + lane) * KP + tc * 4 + slot;
            __builtin_amdgcn_global_load_lds(
                (const __attribute__((address_space(1))) unsigned int*)src,
                (__attribute__((address_space(3))) unsigned int*)&Asl[buf][slot][rh * 64],
                16, 0, 0);
        }
    };

    // ---- prologue: stage tile 0 into buf 0; prefetch tile-1 B inputs ----
    stageA(0, 0);
    {
        uint2 bp0 = qp2[(size_t)(n0 + brow) * 256 + bhalf];
        float s0  = scales[n0 + brow];
        float z0  = zeros [n0 + brow];
        f16x2 s2 = {(_Float16)s0, (_Float16)s0};
        f16x2 z2 = {(_Float16)z0, (_Float16)z0};
        Bsl[0][bhalf * 2 + 0][brow] = dq8(bp0.x, s2, z2);
        Bsl[0][bhalf * 2 + 1][brow] = dq8(bp0.y, s2, z2);
    }
    uint2 bp_n = qp2[(size_t)(n0 + brow) * 256 + 1 * 2 + bhalf];   // tile 1
    float s_n  = scales[n0 + brow];                                // g(1)=0
    float z_n  = zeros [n0 + brow];
    asm volatile("s_waitcnt vmcnt(3) lgkmcnt(0)" ::: "memory");
    __builtin_amdgcn_s_barrier();

    for (int u = 0; u < NT; ++u) {
        const int cur = u & 1;
        const int t   = u + 1;
        const int tc  = (t < NT) ? t : NT - 1;   // tail: redundant-but-safe restage

        // issue next-tile A staging (flies across this tile's MFMA + barrier)
        stageA(tc, cur ^ 1);

        // fragment reads from current buffer
        f16x8 a[8], b[4];
        #pragma unroll
        for (int mf = 0; mf < 8; ++mf)
            a[mf] = *(const f16x8*)&Asl[cur][l4][wm * 128 + mf * 16 + l15];
        #pragma unroll
        for (int nf = 0; nf < 4; ++nf)
            b[nf] = *(const f16x8*)&Bsl[cur][l4][wn * 64 + nf * 16 + l15];

        // dequant tile-t B (inputs prefetched last iter) into next buffer
        {
            f16x2 s2 = {(_Float16)s_n, (_Float16)s_n};
            f16x2 z2 = {(_Float16)z_n, (_Float16)z_n};
            Bsl[cur ^ 1][bhalf * 2 + 0][brow] = dq8(bp_n.x, s2, z2);
            Bsl[cur ^ 1][bhalf * 2 + 1][brow] = dq8(bp_n.y, s2, z2);
        }

        // prefetch tile-(t+1) B inputs (stay in flight across the barrier)
        {
            int t2 = (u + 2 < NT) ? u + 2 : NT - 1;
            int g2 = t2 >> 2;
            bp_n = qp2[(size_t)(n0 + brow) * 256 + t2 * 2 + bhalf];
            s_n  = scales[(size_t)g2 * N_DIM + n0 + brow];
            z_n  = zeros [(size_t)g2 * N_DIM + n0 + brow];
        }

        __builtin_amdgcn_s_setprio(1);
        #pragma unroll
        for (int mf = 0; mf < 8; ++mf)
            #pragma unroll
            for (int nf = 0; nf < 4; ++nf)
                MFMA16(acc[mf][nf], a[mf], b[nf]);
        __builtin_amdgcn_s_setprio(0);

        // publish buf^1: A gll landed (vmcnt 3 leaves bp/s/z flying), B writes drained
        asm volatile("s_waitcnt vmcnt(3) lgkmcnt(0)" ::: "memory");
        __builtin_amdgcn_s_barrier();
    }

    // ---- epilogue: C/D layout col=lane&15, row=(lane>>4)*4+j ----
    #pragma unroll
    for (int nf = 0; nf < 4; ++nf) {
        int col = n0 + wn * 64 + nf * 16 + l15;
        float bv = bias[col];
        #pragma unroll
        for (int mf = 0; mf < 8; ++mf) {
            int rbase = m0 + wm * 128 + mf * 16 + l4 * 4;
            #pragma unroll
            for (int j = 0; j < 4; ++j)
                out[(size_t)(rbase + j) * N_DIM + col] = acc[mf][nf][j] + bv;
        }
    }
}

// ---------- fallback (round-3 proven kernel) if ws too small ----------
__global__ __launch_bounds__(256, 2) void wq_gemm_fb(
    const float* __restrict__ x, const int* __restrict__ qw,
    const float* __restrict__ scales, const float* __restrict__ zeros,
    const float* __restrict__ bias, float* __restrict__ out)
{
    __shared__ __align__(16) _Float16 As[128 * 64];
    __shared__ __align__(16) _Float16 Bs[128 * 64];
    const int tid = threadIdx.x, lane = tid & 63, wid = tid >> 6;
    const int wm = wid >> 1, wn = wid & 1, l15 = lane & 15, l4 = lane >> 4;
    const int m0 = blockIdx.y * 128, n0 = blockIdx.x * 128;
    f32x4 acc[4][4] = {};
    for (int kt = 0; kt < K_DIM / 64; ++kt) {
        const int k0 = kt * 64;
        #pragma unroll
        for (int i = 0; i < 4; ++i) {
            int ci = i * 256 + tid, row = ci >> 3, col = (ci & 7) * 8;
            const float* src = x + (size_t)(m0 + row) * K_DIM + k0 + col;
            float4 f0 = *(const float4*)src; float4 f1 = *(const float4*)(src + 4);
            union { _Float16 h[8]; uint4 v; } pk;
            pk.h[0]=(_Float16)f0.x; pk.h[1]=(_Float16)f0.y; pk.h[2]=(_Float16)f0.z; pk.h[3]=(_Float16)f0.w;
            pk.h[4]=(_Float16)f1.x; pk.h[5]=(_Float16)f1.y; pk.h[6]=(_Float16)f1.z; pk.h[7]=(_Float16)f1.w;
            *(uint4*)(As + ci * 8) = pk.v;
        }
        const int g = k0 >> 7;
        #pragma unroll
        for (int i = 0; i < 4; ++i) {
            int ci = i * 256 + tid, nl = ci >> 3, kc = (ci & 7) * 8;
            const int* qrow = qw + (size_t)(n0 + nl) * K_DIM + k0 + kc;
            int4 q0 = *(const int4*)qrow; int4 q1 = *(const int4*)(qrow + 4);
            float s = scales[(size_t)g * N_DIM + n0 + nl];
            float z = zeros [(size_t)g * N_DIM + n0 + nl];
            union { _Float16 h[8]; uint4 v; } pk;
            pk.h[0]=(_Float16)((float)q0.x*s+z); pk.h[1]=(_Float16)((float)q0.y*s+z);
            pk.h[2]=(_Float16)((float)q0.z*s+z); pk.h[3]=(_Float16)((float)q0.w*s+z);
            pk.h[4]=(_Float16)((float)q1.x*s+z); pk.h[5]=(_Float16)((float)q1.y*s+z);
            pk.h[6]=(_Float16)((float)q1.z*s+z); pk.h[7]=(_Float16)((float)q1.w*s+z);
            *(uint4*)(Bs + ci * 8) = pk.v;
        }
        __syncthreads();
        #pragma unroll
        for (int ks = 0; ks < 2; ++ks) {
            f16x8 a[4], b[4];
            #pragma unroll
            for (int m = 0; m < 4; ++m)
                a[m] = *(const f16x8*)(As + (wm*64 + m*16 + l15) * 64 + ks*32 + l4*8);
            #pragma unroll
            for (int n = 0; n < 4; ++n)
                b[n] = *(const f16x8*)(Bs + (wn*64 + n*16 + l15) * 64 + ks*32 + l4*8);
            #pragma unroll
            for (int m = 0; m < 4; ++m)
                #pragma unroll
                for (int n = 0; n < 4; ++n)
                    MFMA16(acc[m][n], a[m], b[n]);
        }
        __syncthreads();
    }
    #pragma unroll
    for (int n = 0; n < 4; ++n) {
        int col = n0 + wn * 64 + n * 16 + l15;
        float bv = bias[col];
        #pragma unroll
        for (int m = 0; m < 4; ++m) {
            int rbase = m0 + wm * 64 + m * 16 + l4 * 4;
            #pragma unroll
            for (int j = 0; j < 4; ++j)
                out[(size_t)(rbase + j) * N_DIM + col] = acc[m][n][j] + bv;
        }
    }
}

extern "C" void kernel_launch(void* const* d_in, const int* in_sizes, int n_in,
                              void* d_out, int out_size, void* d_ws, size_t ws_size,
                              hipStream_t stream) {
    const float* x  = (const float*)d_in[0];
    const int*   qw = (const int*)d_in[1];
    const float* sc = (const float*)d_in[2];
    const float* zr = (const float*)d_in[3];
    const float* bi = (const float*)d_in[4];
    float* o = (float*)d_out;

    if (ws_size >= WS_NEEDED) {
        unsigned int* qp = (unsigned int*)d_ws;
        uint4* xw = (uint4*)((char*)d_ws + XW_OFFSET);
        pack_qw<<<2048, 256, 0, stream>>>(qw, qp);
        cvt_x  <<<2048, 256, 0, stream>>>(x, xw);
        wq_gemm_p2<<<dim3(1376), dim3(256), 0, stream>>>(
            (const uint4*)xw, (const uint2*)qp, sc, zr, bi, o);
    } else {
        dim3 grid(N_DIM / 128, M_DIM / 128);
        wq_gemm_fb<<<grid, dim3(256), 0, stream>>>(x, qw, sc, zr, bi, o);
    }
}

// Round 7
// 495.113 us; speedup vs baseline: 1.3190x; 1.3190x over previous
//
#include <hip/hip_runtime.h>
#include <stdint.h>

#define M_DIM 4096
#define K_DIM 4096
#define N_DIM 11008
#define KP    512              // 16B slots (8 fp16) per K row of x
#define NT    64               // K tiles of 64
#define BM    128
#define BN    128

#define QP_BYTES   (11008u * 512u * 4u)
#define XW_OFFSET  25165824u
#define XW_BYTES   (4096u * 4096u * 2u)
#define WS_NEEDED  (XW_OFFSET + XW_BYTES)

typedef __attribute__((ext_vector_type(8))) _Float16 f16x8;
typedef __attribute__((ext_vector_type(2))) _Float16 f16x2;
typedef __attribute__((ext_vector_type(4))) float    f32x4;

// ---------- pre-pass 1: qweight int32 [N][K] -> k-major packed u32 qpk[K/8][N] ----------
// nibble layout per word: [3:0]=e0 [7:4]=e2 [11:8]=e4 [15:12]=e6
//                         [19:16]=e1 [23:20]=e3 [27:24]=e5 [31:28]=e7
__global__ void pack_qw(const int* __restrict__ qw, unsigned int* __restrict__ qpk) {
    int n   = blockIdx.x * 256 + threadIdx.x;      // col
    int kw2 = blockIdx.y;                          // pair of k-words (64B read)
    if (n >= N_DIM) return;
    const int* src = qw + (size_t)n * K_DIM + kw2 * 16;
    #pragma unroll
    for (int h = 0; h < 2; ++h) {
        int4 a = *(const int4*)(src + h * 8);
        int4 b = *(const int4*)(src + h * 8 + 4);
        unsigned int w = (unsigned)a.x | ((unsigned)a.z << 4) | ((unsigned)b.x << 8) | ((unsigned)b.z << 12)
                       | ((unsigned)a.y << 16) | ((unsigned)a.w << 20) | ((unsigned)b.y << 24) | ((unsigned)b.w << 28);
        qpk[(size_t)(kw2 * 2 + h) * N_DIM + n] = w;
    }
}

// ---------- pre-pass 2: x fp32 -> fp16 slots, 16B-slot XOR-pre-swizzled (round-4 proven) ----------
__global__ void cvt_x(const float* __restrict__ x, uint4* __restrict__ xw) {
    int stride = gridDim.x * blockDim.x;
    for (int i = blockIdx.x * blockDim.x + threadIdx.x; i < M_DIM * KP; i += stride) {
        int m  = i >> 9;
        int sg = i & 511;
        const float* src = x + ((size_t)m << 12) + sg * 8;
        float4 f0 = *(const float4*)src;
        float4 f1 = *(const float4*)(src + 4);
        union { _Float16 h[8]; uint4 v; } pk;
        pk.h[0]=(_Float16)f0.x; pk.h[1]=(_Float16)f0.y;
        pk.h[2]=(_Float16)f0.z; pk.h[3]=(_Float16)f0.w;
        pk.h[4]=(_Float16)f1.x; pk.h[5]=(_Float16)f1.y;
        pk.h[6]=(_Float16)f1.z; pk.h[7]=(_Float16)f1.w;
        int dst = (sg & ~7) | ((sg & 7) ^ (m & 7));
        xw[((size_t)m << 9) + dst] = pk.v;
    }
}

// ---------- dequant 8 nibbles -> f16x8 fragment (k-order e0..e7) ----------
__device__ __forceinline__ f16x8 dq8(unsigned int w, f16x2 s2, f16x2 z2) {
    const f16x2 k1024 = {(_Float16)1024.0f, (_Float16)1024.0f};
    union { f16x2 h; unsigned int u; } p0, p1, p2, p3;
    p0.u = 0x64006400u | (w & 0x000F000Fu);
    p1.u = 0x64006400u | ((w >> 4)  & 0x000F000Fu);
    p2.u = 0x64006400u | ((w >> 8)  & 0x000F000Fu);
    p3.u = 0x64006400u | ((w >> 12) & 0x000F000Fu);
    union { f16x2 h2[4]; f16x8 v; } r;
    r.h2[0] = (p0.h - k1024) * s2 + z2;
    r.h2[1] = (p1.h - k1024) * s2 + z2;
    r.h2[2] = (p2.h - k1024) * s2 + z2;
    r.h2[3] = (p3.h - k1024) * s2 + z2;
    return r.v;
}

#define MFMA16(d, va, vb) d = __builtin_amdgcn_mfma_f32_16x16x32_f16(va, vb, d, 0, 0, 0)

// ---------- main GEMM: 128x128 tile, A dbuf in LDS, B dequant in registers ----------
__global__ __launch_bounds__(256, 3) void wq_gemm_breg(
    const uint4*        __restrict__ xw,     // fp16 [M][512] slots, pre-swizzled
    const unsigned int* __restrict__ qpk,    // packed u32 [512][N] (k-major)
    const float*        __restrict__ scales, // fp32 [32][N]
    const float*        __restrict__ zeros,  // fp32 [32][N]
    const float*        __restrict__ bias,   // fp32 [N]
    float*              __restrict__ out)    // fp32 [M][N]
{
    __shared__ __align__(16) uint4 Asl[2][1024];   // [buf][row*8 + swz_slot], 32 KB

    const int tid  = threadIdx.x;
    const int lane = tid & 63;
    const int wid  = tid >> 6;
    const int wm   = wid >> 1;          // 0..1
    const int wn   = wid & 1;           // 0..1
    const int l15  = lane & 15;
    const int l4   = lane >> 4;         // 0..3

    const int m0 = blockIdx.y * BM;
    const int n0 = blockIdx.x * BN;
    const int colbase = n0 + wn * 64 + l15;   // + n*16 per fragment

    f32x4 acc[4][4] = {};

    auto stageA = [&](int t, int b) {
        #pragma unroll
        for (int i = 0; i < 4; ++i) {
            int off16 = i * 256 + tid;
            int row   = off16 >> 3;
            int sl    = off16 & 7;
            const uint4* gsrc = xw + (size_t)(m0 + row) * KP + t * 8 + sl;
            __builtin_amdgcn_global_load_lds(
                (const __attribute__((address_space(1))) unsigned int*)gsrc,
                (__attribute__((address_space(3))) unsigned int*)&Asl[b][off16],
                16, 0, 0);
        }
    };

    // ---- prologue: tile-0 scales + A staging + B words (issue order matters for ledger) ----
    float s_p[4], z_p[4], s_n[4], z_n[4];
    unsigned int wq_p[8], wq_n[8];
    #pragma unroll
    for (int n = 0; n < 4; ++n) {            // 8 loads (oldest)
        s_p[n] = scales[colbase + n * 16];
        z_p[n] = zeros [colbase + n * 16];
    }
    stageA(0, 0);                            // 4 gll
    #pragma unroll
    for (int n = 0; n < 4; ++n)
        #pragma unroll
        for (int ks = 0; ks < 2; ++ks)       // 8 word loads (newest)
            wq_p[n * 2 + ks] = qpk[(size_t)(ks * 4 + l4) * N_DIM + colbase + n * 16];
    asm volatile("s_waitcnt vmcnt(8)" ::: "memory");   // drain scales + gll; words fly
    __builtin_amdgcn_s_barrier();

    for (int u = 0; u < NT; ++u) {
        const int cur = u & 1;
        const int tc  = (u + 1 < NT) ? u + 1 : NT - 1;
        const int gn  = tc >> 1;

        // 1. prefetch next scales/zeros (8 loads, oldest of this iter)
        #pragma unroll
        for (int n = 0; n < 4; ++n) {
            s_n[n] = scales[(size_t)gn * N_DIM + colbase + n * 16];
            z_n[n] = zeros [(size_t)gn * N_DIM + colbase + n * 16];
        }
        // 2. stage next A tile (4 gll)
        stageA(tc, cur ^ 1);
        // 3. prefetch next B words (8 loads, newest)
        #pragma unroll
        for (int n = 0; n < 4; ++n)
            #pragma unroll
            for (int ks = 0; ks < 2; ++ks)
                wq_n[n * 2 + ks] = qpk[(size_t)(tc * 8 + ks * 4 + l4) * N_DIM + colbase + n * 16];

        // 4. A fragments from published buffer (XOR-deswizzled, conflict-free)
        f16x8 a[4][2];
        #pragma unroll
        for (int m = 0; m < 4; ++m)
            #pragma unroll
            for (int ks = 0; ks < 2; ++ks) {
                int row = wm * 64 + m * 16 + l15;
                a[m][ks] = *(const f16x8*)&Asl[cur][row * 8 + ((ks * 4 + l4) ^ (row & 7))];
            }

        // 5. dequant current B words straight into fragments
        f16x8 b[4][2];
        #pragma unroll
        for (int n = 0; n < 4; ++n) {
            f16x2 s2 = {(_Float16)s_p[n], (_Float16)s_p[n]};
            f16x2 z2 = {(_Float16)z_p[n], (_Float16)z_p[n]};
            #pragma unroll
            for (int ks = 0; ks < 2; ++ks)
                b[n][ks] = dq8(wq_p[n * 2 + ks], s2, z2);
        }

        // 6. MFMA cluster: 32 per barrier
        #pragma unroll
        for (int m = 0; m < 4; ++m)
            #pragma unroll
            for (int n = 0; n < 4; ++n)
                #pragma unroll
                for (int ks = 0; ks < 2; ++ks)
                    MFMA16(acc[m][n], a[m][ks], b[n][ks]);

        // 7. rotate prefetched state
        #pragma unroll
        for (int i = 0; i < 8; ++i) wq_p[i] = wq_n[i];
        #pragma unroll
        for (int n = 0; n < 4; ++n) { s_p[n] = s_n[n]; z_p[n] = z_n[n]; }

        // 8. publish next buffer: drain scales+gll (8 words stay in flight), barrier
        asm volatile("s_waitcnt vmcnt(8)" ::: "memory");
        __builtin_amdgcn_s_barrier();
    }

    // ---- epilogue: C/D layout col=lane&15, row=(lane>>4)*4+j ----
    #pragma unroll
    for (int n = 0; n < 4; ++n) {
        int col = n0 + wn * 64 + n * 16 + l15;
        float bv = bias[col];
        #pragma unroll
        for (int m = 0; m < 4; ++m) {
            int rbase = m0 + wm * 64 + m * 16 + l4 * 4;
            #pragma unroll
            for (int j = 0; j < 4; ++j)
                out[(size_t)(rbase + j) * N_DIM + col] = acc[m][n][j] + bv;
        }
    }
}

// ---------- fallback (round-3 proven kernel) if ws too small ----------
__global__ __launch_bounds__(256, 2) void wq_gemm_fb(
    const float* __restrict__ x, const int* __restrict__ qw,
    const float* __restrict__ scales, const float* __restrict__ zeros,
    const float* __restrict__ bias, float* __restrict__ out)
{
    __shared__ __align__(16) _Float16 As[128 * 64];
    __shared__ __align__(16) _Float16 Bs[128 * 64];
    const int tid = threadIdx.x, lane = tid & 63, wid = tid >> 6;
    const int wm = wid >> 1, wn = wid & 1, l15 = lane & 15, l4 = lane >> 4;
    const int m0 = blockIdx.y * 128, n0 = blockIdx.x * 128;
    f32x4 acc[4][4] = {};
    for (int kt = 0; kt < K_DIM / 64; ++kt) {
        const int k0 = kt * 64;
        #pragma unroll
        for (int i = 0; i < 4; ++i) {
            int ci = i * 256 + tid, row = ci >> 3, col = (ci & 7) * 8;
            const float* src = x + (size_t)(m0 + row) * K_DIM + k0 + col;
            float4 f0 = *(const float4*)src; float4 f1 = *(const float4*)(src + 4);
            union { _Float16 h[8]; uint4 v; } pk;
            pk.h[0]=(_Float16)f0.x; pk.h[1]=(_Float16)f0.y; pk.h[2]=(_Float16)f0.z; pk.h[3]=(_Float16)f0.w;
            pk.h[4]=(_Float16)f1.x; pk.h[5]=(_Float16)f1.y; pk.h[6]=(_Float16)f1.z; pk.h[7]=(_Float16)f1.w;
            *(uint4*)(As + ci * 8) = pk.v;
        }
        const int g = k0 >> 7;
        #pragma unroll
        for (int i = 0; i < 4; ++i) {
            int ci = i * 256 + tid, nl = ci >> 3, kc = (ci & 7) * 8;
            const int* qrow = qw + (size_t)(n0 + nl) * K_DIM + k0 + kc;
            int4 q0 = *(const int4*)qrow; int4 q1 = *(const int4*)(qrow + 4);
            float s = scales[(size_t)g * N_DIM + n0 + nl];
            float z = zeros [(size_t)g * N_DIM + n0 + nl];
            union { _Float16 h[8]; uint4 v; } pk;
            pk.h[0]=(_Float16)((float)q0.x*s+z); pk.h[1]=(_Float16)((float)q0.y*s+z);
            pk.h[2]=(_Float16)((float)q0.z*s+z); pk.h[3]=(_Float16)((float)q0.w*s+z);
            pk.h[4]=(_Float16)((float)q1.x*s+z); pk.h[5]=(_Float16)((float)q1.y*s+z);
            pk.h[6]=(_Float16)((float)q1.z*s+z); pk.h[7]=(_Float16)((float)q1.w*s+z);
            *(uint4*)(Bs + ci * 8) = pk.v;
        }
        __syncthreads();
        #pragma unroll
        for (int ks = 0; ks < 2; ++ks) {
            f16x8 a[4], b[4];
            #pragma unroll
            for (int m = 0; m < 4; ++m)
                a[m] = *(const f16x8*)(As + (wm*64 + m*16 + l15) * 64 + ks*32 + l4*8);
            #pragma unroll
            for (int n = 0; n < 4; ++n)
                b[n] = *(const f16x8*)(Bs + (wn*64 + n*16 + l15) * 64 + ks*32 + l4*8);
            #pragma unroll
            for (int m = 0; m < 4; ++m)
                #pragma unroll
                for (int n = 0; n < 4; ++n)
                    MFMA16(acc[m][n], a[m], b[n]);
        }
        __syncthreads();
    }
    #pragma unroll
    for (int n = 0; n < 4; ++n) {
        int col = n0 + wn * 64 + n * 16 + l15;
        float bv = bias[col];
        #pragma unroll
        for (int m = 0; m < 4; ++m) {
            int rbase = m0 + wm * 64 + m * 16 + l4 * 4;
            #pragma unroll
            for (int j = 0; j < 4; ++j)
                out[(size_t)(rbase + j) * N_DIM + col] = acc[m][n][j] + bv;
        }
    }
}

extern "C" void kernel_launch(void* const* d_in, const int* in_sizes, int n_in,
                              void* d_out, int out_size, void* d_ws, size_t ws_size,
                              hipStream_t stream) {
    const float* x  = (const float*)d_in[0];
    const int*   qw = (const int*)d_in[1];
    const float* sc = (const float*)d_in[2];
    const float* zr = (const float*)d_in[3];
    const float* bi = (const float*)d_in[4];
    float* o = (float*)d_out;

    dim3 grid(N_DIM / BN, M_DIM / BM);   // 86 x 32

    if (ws_size >= WS_NEEDED) {
        unsigned int* qpk = (unsigned int*)d_ws;
        uint4* xw = (uint4*)((char*)d_ws + XW_OFFSET);
        pack_qw<<<dim3((N_DIM + 255) / 256, 256), dim3(256), 0, stream>>>(qw, qpk);
        cvt_x  <<<2048, 256, 0, stream>>>(x, xw);
        wq_gemm_breg<<<grid, dim3(256), 0, stream>>>(
            (const uint4*)xw, qpk, sc, zr, bi, o);
    } else {
        wq_gemm_fb<<<grid, dim3(256), 0, stream>>>(x, qw, sc, zr, bi, o);
    }
}